// Round 1
// baseline (406.720 us; speedup 1.0000x reference)
//
#include <hip/hip_runtime.h>
#include <stdint.h>

#define BATCH  256
#define CDIM   2048
#define HW     49
#define NTOK   50
#define MROWS  (BATCH * NTOK)   // 12800
#define ODIM   1024
#define NHEADS 32
#define HD     64

typedef __attribute__((ext_vector_type(8))) short short8;
typedef __attribute__((ext_vector_type(4))) float f32x4;
typedef unsigned short u16;
typedef unsigned int   u32;

__device__ __forceinline__ float bf2f(u16 u) {
  union { u32 i; float f; } v; v.i = ((u32)u) << 16; return v.f;
}
__device__ __forceinline__ u16 f2bf(float f) {
  union { float f; u32 i; } v; v.f = f;
  u32 r = v.i + 0x7fffu + ((v.i >> 16) & 1u);   // round-to-nearest-even
  return (u16)(r >> 16);
}

// async global->LDS, 16 bytes per lane (wave-uniform base + lane*16 dest)
__device__ __forceinline__ void async16(const void* g, void* l) {
  __builtin_amdgcn_global_load_lds(
      (const __attribute__((address_space(1))) u32*)g,
      (__attribute__((address_space(3))) u32*)l, 16, 0, 0);
}

// ---------------- fp32 -> bf16 weight convert ----------------
__global__ __launch_bounds__(256) void cvt_kernel(const float* __restrict__ in,
                                                  u16* __restrict__ out, int n4) {
  int i = blockIdx.x * 256 + threadIdx.x;
  if (i >= n4) return;
  float4 v = reinterpret_cast<const float4*>(in)[i];
  ushort4 o;
  o.x = f2bf(v.x); o.y = f2bf(v.y); o.z = f2bf(v.z); o.w = f2bf(v.w);
  reinterpret_cast<ushort4*>(out)[i] = o;
}

// ---------------- token prep: x[B,C,49] -> T[B*50, C] bf16 ----------------
// t[b,0,:] = mean_s x[b,:,s] + pos[0]; t[b,n,:] = x[b,:,n-1] + pos[n]
__global__ __launch_bounds__(256) void prep_kernel(const float* __restrict__ x,
                                                   const float* __restrict__ pos,
                                                   u16* __restrict__ T) {
  const int blk = blockIdx.x;
  const int b  = blk >> 5;             // 32 chunks of 64 channels
  const int c0 = (blk & 31) * 64;
  __shared__ float xs[64 * HW];        // 12.5 KB
  __shared__ float mean[64];
  const float* src = x + ((size_t)b * CDIM + c0) * HW;  // 64*49 contiguous floats
  for (int i = threadIdx.x; i < 64 * HW; i += 256) xs[i] = src[i];
  __syncthreads();
  if (threadIdx.x < 64) {
    float s = 0.f;
#pragma unroll
    for (int j = 0; j < HW; j++) s += xs[threadIdx.x * HW + j];
    mean[threadIdx.x] = s * (1.0f / 49.0f);
  }
  __syncthreads();
  // 50 tokens x 8 groups of 8 channels; each item writes 16B coalesced
  for (int wi = threadIdx.x; wi < NTOK * 8; wi += 256) {
    const int n = wi >> 3;
    const int g = (wi & 7) * 8;
    alignas(16) u16 ov[8];
#pragma unroll
    for (int u = 0; u < 8; u++) {
      const int c = g + u;
      float val = (n == 0) ? mean[c] : xs[c * HW + (n - 1)];
      val += pos[n * CDIM + c0 + c];
      ov[u] = f2bf(val);
    }
    *reinterpret_cast<uint4*>(&T[((size_t)b * NTOK + n) * CDIM + c0 + g]) =
        *reinterpret_cast<const uint4*>(ov);
  }
}

// ---------------- GEMM (B^T layout): C[M,N] = A[M,K] * Bm[N,K]^T + bias ----
// m97 structure: 128x128 tile, BK=64, 4 waves (2x2), 4x4 fragments of
// mfma_f32_16x16x32_bf16, global_load_lds width-16 staging.
template<int OUT_BF16>
__global__ __launch_bounds__(256) void gemm_bt(const u16* __restrict__ A,
                                               const u16* __restrict__ Bm,
                                               const float* __restrict__ bias,
                                               void* __restrict__ Cout,
                                               int M, int N, int K) {
  constexpr int BM = 128, BN = 128, BK = 64;
  __shared__ __align__(16) u16 As[BM * BK];   // 16 KB
  __shared__ __align__(16) u16 Bs[BN * BK];   // 16 KB
  const int t  = threadIdx.x;
  const int lane = t & 63;
  const int w  = t >> 6;
  const int wm = w >> 1, wn = w & 1;          // 2x2 wave grid, 64x64 per wave
  const int m0 = blockIdx.y * BM, n0 = blockIdx.x * BN;

  const int rr = t >> 3;                      // staging row within 32-row chunk
  const int ce = (t & 7) * 8;                 // staging col (elements)

  f32x4 acc[4][4] = {};

  const int lr = lane & 15;                   // fragment row (A) / col (B)
  const int kq = (lane >> 4) * 8;             // k-chunk within 32

  for (int kt = 0; kt < K; kt += BK) {
#pragma unroll
    for (int i = 0; i < 4; i++) {             // A tile: 128 x 64
      const u16* gp = A + (size_t)(m0 + i * 32 + rr) * K + kt + ce;
      async16(gp, &As[i * 2048 + t * 8]);
    }
#pragma unroll
    for (int i = 0; i < 4; i++) {             // B tile: 128 x 64
      const u16* gp = Bm + (size_t)(n0 + i * 32 + rr) * K + kt + ce;
      async16(gp, &Bs[i * 2048 + t * 8]);
    }
    __syncthreads();                          // drains vmcnt before barrier
#pragma unroll
    for (int kk = 0; kk < 2; kk++) {
      const int lk = kk * 32 + kq;
      short8 af[4], bf[4];
#pragma unroll
      for (int f = 0; f < 4; f++)
        af[f] = *reinterpret_cast<const short8*>(&As[(wm * 64 + f * 16 + lr) * BK + lk]);
#pragma unroll
      for (int f = 0; f < 4; f++)
        bf[f] = *reinterpret_cast<const short8*>(&Bs[(wn * 64 + f * 16 + lr) * BK + lk]);
#pragma unroll
      for (int fm = 0; fm < 4; fm++)
#pragma unroll
        for (int fn = 0; fn < 4; fn++)
          acc[fm][fn] = __builtin_amdgcn_mfma_f32_16x16x32_bf16(
              af[fm], bf[fn], acc[fm][fn], 0, 0, 0);
    }
    __syncthreads();
  }

  // epilogue: C/D layout col=lane&15, row=(lane>>4)*4+j  [m89/m91]
  const int erow = (lane >> 4) * 4;
#pragma unroll
  for (int fm = 0; fm < 4; fm++) {
#pragma unroll
    for (int fn = 0; fn < 4; fn++) {
      const int cg = n0 + wn * 64 + fn * 16 + lr;
      const float bb = bias[cg];
#pragma unroll
      for (int j = 0; j < 4; j++) {
        const int rg = m0 + wm * 64 + fm * 16 + erow + j;
        const float val = acc[fm][fn][j] + bb;
        if (OUT_BF16)
          ((u16*)Cout)[(size_t)rg * N + cg] = f2bf(val);
        else
          ((float*)Cout)[(size_t)rg * N + cg] = val;
      }
    }
  }
}

// ---------------- token-0 attention, per (b,h), in-place on V ----------------
__global__ __launch_bounds__(64) void attn0_kernel(u16* __restrict__ V) {
  const int b = blockIdx.x, h = blockIdx.y;
  __shared__ __align__(16) u16 vt[NTOK * HD];  // 6.4 KB
  __shared__ float pb[64];
  const int t = threadIdx.x;
  u16* base = V + (size_t)b * NTOK * CDIM + h * HD;
  for (int idx = t; idx < NTOK * 8; idx += 64) {
    const int m = idx >> 3, g = (idx & 7) * 8;
    *reinterpret_cast<uint4*>(&vt[m * HD + g]) =
        *reinterpret_cast<const uint4*>(base + (size_t)m * CDIM + g);
  }
  __syncthreads();
  const float qd = bf2f(vt[t]);               // q = token 0
  float s_own = -1e30f;
  for (int m = 0; m < NTOK; m++) {
    float p = qd * bf2f(vt[m * HD + t]);
#pragma unroll
    for (int off = 32; off; off >>= 1) p += __shfl_xor(p, off);
    if (t == m) s_own = p * 0.125f;           // scale = hd^-0.5 = 1/8
  }
  float mx = s_own;
#pragma unroll
  for (int off = 32; off; off >>= 1) mx = fmaxf(mx, __shfl_xor(mx, off));
  const float e = (t < NTOK) ? __expf(s_own - mx) : 0.f;
  float Z = e;
#pragma unroll
  for (int off = 32; off; off >>= 1) Z += __shfl_xor(Z, off);
  pb[t] = e / Z;
  __syncthreads();
  float acc = 0.f;
  for (int m = 0; m < NTOK; m++) acc += pb[m] * bf2f(vt[m * HD + t]);
  base[t] = f2bf(acc);                        // overwrite v[b,0,h*64+t] with ctx0
}

// ---------------- launch ----------------
extern "C" void kernel_launch(void* const* d_in, const int* in_sizes, int n_in,
                              void* d_out, int out_size, void* d_ws, size_t ws_size,
                              hipStream_t stream) {
  const float* x   = (const float*)d_in[0];
  const float* pos = (const float*)d_in[1];
  const float* Wv  = (const float*)d_in[2];
  const float* bv  = (const float*)d_in[3];
  const float* Wc  = (const float*)d_in[4];
  const float* bc  = (const float*)d_in[5];
  float* out = (float*)d_out;

  u16* T   = (u16*)d_ws;                        // [12800][2048] bf16
  u16* V   = T   + (size_t)MROWS * CDIM;        // [12800][2048] bf16
  u16* WvB = V   + (size_t)MROWS * CDIM;        // [2048][2048]  bf16
  u16* WcB = WvB + (size_t)CDIM * CDIM;         // [1024][2048]  bf16
  // total ws use: 112 MB

  {
    int n4 = CDIM * CDIM / 4;
    cvt_kernel<<<(n4 + 255) / 256, 256, 0, stream>>>(Wv, WvB, n4);
  }
  {
    int n4 = ODIM * CDIM / 4;
    cvt_kernel<<<(n4 + 255) / 256, 256, 0, stream>>>(Wc, WcB, n4);
  }
  prep_kernel<<<BATCH * 32, 256, 0, stream>>>(x, pos, T);

  gemm_bt<1><<<dim3(CDIM / 128, MROWS / 128), 256, 0, stream>>>(
      T, WvB, bv, V, MROWS, CDIM, CDIM);

  attn0_kernel<<<dim3(BATCH, NHEADS), 64, 0, stream>>>(V);

  gemm_bt<0><<<dim3(ODIM / 128, MROWS / 128), 256, 0, stream>>>(
      V, WcB, bc, out, MROWS, ODIM, CDIM);
}

// Round 2
// 309.867 us; speedup vs baseline: 1.3126x; 1.3126x over previous
//
#include <hip/hip_runtime.h>
#include <stdint.h>

#define BATCH  256
#define CDIM   2048
#define HW     49
#define NTOK   50
#define MROWS  (BATCH * NTOK)   // 12800
#define ODIM   1024
#define NHEADS 32

typedef __attribute__((ext_vector_type(8))) short short8;
typedef __attribute__((ext_vector_type(4))) float f32x4;
typedef unsigned short u16;
typedef unsigned int   u32;

__device__ __forceinline__ float bf2f(u16 u) {
  union { u32 i; float f; } v; v.i = ((u32)u) << 16; return v.f;
}
__device__ __forceinline__ u16 f2bf(float f) {
  union { float f; u32 i; } v; v.f = f;
  u32 r = v.i + 0x7fffu + ((v.i >> 16) & 1u);   // round-to-nearest-even
  return (u16)(r >> 16);
}

// async global->LDS, 16 bytes per lane (wave-uniform base + lane*16 dest)
__device__ __forceinline__ void async16(const void* g, void* l) {
  __builtin_amdgcn_global_load_lds(
      (const __attribute__((address_space(1))) u32*)g,
      (__attribute__((address_space(3))) u32*)l, 16, 0, 0);
}

// ---------------- fp32 -> bf16 weight convert ----------------
__global__ __launch_bounds__(256) void cvt_kernel(const float* __restrict__ in,
                                                  u16* __restrict__ out, int n4) {
  int i = blockIdx.x * 256 + threadIdx.x;
  if (i >= n4) return;
  float4 v = reinterpret_cast<const float4*>(in)[i];
  ushort4 o;
  o.x = f2bf(v.x); o.y = f2bf(v.y); o.z = f2bf(v.z); o.w = f2bf(v.w);
  reinterpret_cast<ushort4*>(out)[i] = o;
}

// ---------------- token prep: x[B,C,49] -> T[B*50, C] bf16 ----------------
__global__ __launch_bounds__(256) void prep_kernel(const float* __restrict__ x,
                                                   const float* __restrict__ pos,
                                                   u16* __restrict__ T) {
  const int blk = blockIdx.x;
  const int b  = blk >> 5;             // 32 chunks of 64 channels
  const int c0 = (blk & 31) * 64;
  __shared__ float xs[64 * HW];
  __shared__ float mean[64];
  const float* src = x + ((size_t)b * CDIM + c0) * HW;
  for (int i = threadIdx.x; i < 64 * HW; i += 256) xs[i] = src[i];
  __syncthreads();
  if (threadIdx.x < 64) {
    float s = 0.f;
#pragma unroll
    for (int j = 0; j < HW; j++) s += xs[threadIdx.x * HW + j];
    mean[threadIdx.x] = s * (1.0f / 49.0f);
  }
  __syncthreads();
  for (int wi = threadIdx.x; wi < NTOK * 8; wi += 256) {
    const int n = wi >> 3;
    const int g = (wi & 7) * 8;
    alignas(16) u16 ov[8];
#pragma unroll
    for (int u = 0; u < 8; u++) {
      const int c = g + u;
      float val = (n == 0) ? mean[c] : xs[c * HW + (n - 1)];
      val += pos[n * CDIM + c0 + c];
      ov[u] = f2bf(val);
    }
    *reinterpret_cast<uint4*>(&T[((size_t)b * NTOK + n) * CDIM + c0 + g]) =
        *reinterpret_cast<const uint4*>(ov);
  }
}

// ---------------- 256x256 8-phase GEMM (B^T): C = A[M,K]*Bm[N,K]^T + bias ----
// T1 XCD swizzle + T2 granule-XOR swizzle + T3/T4 phased counted-vmcnt + T5.
// LDS: 2 K-tile dbuf x (A[256][64] | B[256][64]) bf16 = 128 KiB.
// Staging slots: s = 4*kti + {0:A-h0, 1:A-h1, 2:B-h0, 3:B-h1}; slot s staged
// at global phase s-6; per-wave 2 gload_lds per phase; vmcnt(4) per K-tile.
template<int OUT_BF16>
__global__ __launch_bounds__(512, 2)
void gemm256(const u16* __restrict__ A, const u16* __restrict__ Bm,
             const float* __restrict__ bias, void* __restrict__ Cout,
             int M, int N, int K, int nbx) {
  __shared__ __align__(16) u16 smem[65536];   // 128 KiB

  const int NK = K >> 6;
  const int t = threadIdx.x;
  const int lane = t & 63;
  const int wid = t >> 6;
  const int wm = wid >> 2;          // 0..1
  const int wn = wid & 3;           // 0..3

  // bijective XCD swizzle (gridDim.x % 8 == 0)
  const int nwg = gridDim.x;
  const int cpx = nwg >> 3;
  const int orig = blockIdx.x;
  const int swz = (orig & 7) * cpx + (orig >> 3);
  const int bx = swz % nbx;
  const int by = swz / nbx;
  const int m0 = by * 256, n0 = bx * 256;

  // staging source (pre-swizzled octet so linear LDS dest = swizzled layout)
  const int tr  = t >> 3;
  const int to8 = ((t & 7) ^ (tr & 7)) << 3;
  const int t8  = t << 3;
  const u16* pA0 = A  + (size_t)(m0 + tr) * K + to8;
  const u16* pB0 = Bm + (size_t)(n0 + tr) * K + to8;

  // ds_read offsets (elements), granule g=kk*4+hi XORed with row&7 (=lr&7)
  const int lr = lane & 15, hi = lane >> 4;
  const int sx = lr & 7;
  const int aK0 = ((wm * 128 + lr) << 6) + (((0 + hi) ^ sx) << 3);
  const int aK1 = ((wm * 128 + lr) << 6) + (((4 + hi) ^ sx) << 3);
  const int bK0 = 16384 + ((wn * 64 + lr) << 6) + (((0 + hi) ^ sx) << 3);
  const int bK1 = 16384 + ((wn * 64 + lr) << 6) + (((4 + hi) ^ sx) << 3);

  f32x4 acc[8][4] = {};
  short8 af[8][2], bf[4][2];

  auto STAGE = [&](int s) {
    if (s < 4 * NK) {
      const int kti = s >> 2;
      const int isB = (s >> 1) & 1;
      const int h   = s & 1;
      const u16* g = (isB ? pB0 : pA0) + (size_t)(h * 128) * K + kti * 64;
      u16* l = &smem[((kti & 1) << 15) + (isB << 14) + (h << 13) + t8];
      async16(g, l);
      async16(g + (size_t)64 * K, l + 4096);
    }
  };

  // prologue: K-tile0 (A0,A1,B0,B1) + K-tile1 (A0,A1); 2 half-tiles in flight
#pragma unroll
  for (int s = 0; s < 6; ++s) STAGE(s);
  asm volatile("s_waitcnt vmcnt(4)" ::: "memory");
  __builtin_amdgcn_s_barrier();

  for (int j = 0; j < NK; ++j) {
    const u16* sa = &smem[(j & 1) << 15];

    // ---- phase 0: read af[0..3], bf[0..1]; stage B-h0 of j+1 ----
#pragma unroll
    for (int f = 0; f < 4; ++f) {
      af[f][0] = *(const short8*)&sa[aK0 + f * 1024];
      af[f][1] = *(const short8*)&sa[aK1 + f * 1024];
    }
#pragma unroll
    for (int f = 0; f < 2; ++f) {
      bf[f][0] = *(const short8*)&sa[bK0 + f * 1024];
      bf[f][1] = *(const short8*)&sa[bK1 + f * 1024];
    }
    STAGE(4 * j + 6);
    __builtin_amdgcn_s_barrier();
    asm volatile("s_waitcnt lgkmcnt(0)" ::: "memory");
    __builtin_amdgcn_sched_barrier(0);
    __builtin_amdgcn_s_setprio(1);
#pragma unroll
    for (int fm = 0; fm < 4; ++fm)
#pragma unroll
      for (int fn = 0; fn < 2; ++fn) {
        acc[fm][fn] = __builtin_amdgcn_mfma_f32_16x16x32_bf16(af[fm][0], bf[fn][0], acc[fm][fn], 0, 0, 0);
        acc[fm][fn] = __builtin_amdgcn_mfma_f32_16x16x32_bf16(af[fm][1], bf[fn][1], acc[fm][fn], 0, 0, 0);
      }
    __builtin_amdgcn_s_setprio(0);
    __builtin_amdgcn_s_barrier();

    // ---- phase 1: read af[4..7], bf[2..3]; stage B-h1 of j+1 ----
#pragma unroll
    for (int f = 4; f < 8; ++f) {
      af[f][0] = *(const short8*)&sa[aK0 + f * 1024];
      af[f][1] = *(const short8*)&sa[aK1 + f * 1024];
    }
#pragma unroll
    for (int f = 2; f < 4; ++f) {
      bf[f][0] = *(const short8*)&sa[bK0 + f * 1024];
      bf[f][1] = *(const short8*)&sa[bK1 + f * 1024];
    }
    STAGE(4 * j + 7);
    __builtin_amdgcn_s_barrier();
    asm volatile("s_waitcnt lgkmcnt(0)" ::: "memory");
    __builtin_amdgcn_sched_barrier(0);
    __builtin_amdgcn_s_setprio(1);
#pragma unroll
    for (int fm = 4; fm < 8; ++fm)
#pragma unroll
      for (int fn = 0; fn < 2; ++fn) {
        acc[fm][fn] = __builtin_amdgcn_mfma_f32_16x16x32_bf16(af[fm][0], bf[fn][0], acc[fm][fn], 0, 0, 0);
        acc[fm][fn] = __builtin_amdgcn_mfma_f32_16x16x32_bf16(af[fm][1], bf[fn][1], acc[fm][fn], 0, 0, 0);
      }
    __builtin_amdgcn_s_setprio(0);
    __builtin_amdgcn_s_barrier();

    // ---- phase 2: stage A-h0 of j+2 (buf fully consumed by all waves) ----
    STAGE(4 * j + 8);
    __builtin_amdgcn_s_barrier();
    __builtin_amdgcn_s_setprio(1);
#pragma unroll
    for (int fm = 0; fm < 4; ++fm)
#pragma unroll
      for (int fn = 2; fn < 4; ++fn) {
        acc[fm][fn] = __builtin_amdgcn_mfma_f32_16x16x32_bf16(af[fm][0], bf[fn][0], acc[fm][fn], 0, 0, 0);
        acc[fm][fn] = __builtin_amdgcn_mfma_f32_16x16x32_bf16(af[fm][1], bf[fn][1], acc[fm][fn], 0, 0, 0);
      }
    __builtin_amdgcn_s_setprio(0);
    __builtin_amdgcn_s_barrier();

    // ---- phase 3: stage A-h1 of j+2; counted vmcnt, drain only at tail ----
    STAGE(4 * j + 9);
    __builtin_amdgcn_s_barrier();
    __builtin_amdgcn_s_setprio(1);
#pragma unroll
    for (int fm = 4; fm < 8; ++fm)
#pragma unroll
      for (int fn = 2; fn < 4; ++fn) {
        acc[fm][fn] = __builtin_amdgcn_mfma_f32_16x16x32_bf16(af[fm][0], bf[fn][0], acc[fm][fn], 0, 0, 0);
        acc[fm][fn] = __builtin_amdgcn_mfma_f32_16x16x32_bf16(af[fm][1], bf[fn][1], acc[fm][fn], 0, 0, 0);
      }
    __builtin_amdgcn_s_setprio(0);
    if (j < NK - 2) asm volatile("s_waitcnt vmcnt(4)" ::: "memory");
    else            asm volatile("s_waitcnt vmcnt(0)" ::: "memory");
    __builtin_amdgcn_s_barrier();
  }

  // epilogue: C/D layout col=lane&15, row=(lane>>4)*4+j
  const int erow = hi * 4;
#pragma unroll
  for (int fm = 0; fm < 8; ++fm) {
#pragma unroll
    for (int fn = 0; fn < 4; ++fn) {
      const int cg = n0 + wn * 64 + fn * 16 + lr;
      const float bb = bias[cg];
      const int rbase = m0 + wm * 128 + fm * 16 + erow;
#pragma unroll
      for (int jr = 0; jr < 4; ++jr) {
        const float val = acc[fm][fn][jr] + bb;
        if (OUT_BF16)
          ((u16*)Cout)[(size_t)(rbase + jr) * N + cg] = f2bf(val);
        else
          ((float*)Cout)[(size_t)(rbase + jr) * N + cg] = val;
      }
    }
  }
}

// ---------------- token-0 attention, per (b,h), in-place on V ----------------
__global__ __launch_bounds__(64) void attn0_kernel(u16* __restrict__ V) {
  const int b = blockIdx.x, h = blockIdx.y;
  __shared__ __align__(16) u16 vt[NTOK * 64];
  __shared__ float pb[64];
  const int t = threadIdx.x;
  u16* base = V + (size_t)b * NTOK * CDIM + h * 64;
  for (int idx = t; idx < NTOK * 8; idx += 64) {
    const int m = idx >> 3, g = (idx & 7) * 8;
    *reinterpret_cast<uint4*>(&vt[m * 64 + g]) =
        *reinterpret_cast<const uint4*>(base + (size_t)m * CDIM + g);
  }
  __syncthreads();
  const float qd = bf2f(vt[t]);
  float s_own = -1e30f;
  for (int m = 0; m < NTOK; m++) {
    float p = qd * bf2f(vt[m * 64 + t]);
#pragma unroll
    for (int off = 32; off; off >>= 1) p += __shfl_xor(p, off);
    if (t == m) s_own = p * 0.125f;
  }
  float mx = s_own;
#pragma unroll
  for (int off = 32; off; off >>= 1) mx = fmaxf(mx, __shfl_xor(mx, off));
  const float e = (t < NTOK) ? __expf(s_own - mx) : 0.f;
  float Z = e;
#pragma unroll
  for (int off = 32; off; off >>= 1) Z += __shfl_xor(Z, off);
  pb[t] = e / Z;
  __syncthreads();
  float acc = 0.f;
  for (int m = 0; m < NTOK; m++) acc += pb[m] * bf2f(vt[m * 64 + t]);
  base[t] = f2bf(acc);
}

// ---------------- launch ----------------
extern "C" void kernel_launch(void* const* d_in, const int* in_sizes, int n_in,
                              void* d_out, int out_size, void* d_ws, size_t ws_size,
                              hipStream_t stream) {
  const float* x   = (const float*)d_in[0];
  const float* pos = (const float*)d_in[1];
  const float* Wv  = (const float*)d_in[2];
  const float* bv  = (const float*)d_in[3];
  const float* Wc  = (const float*)d_in[4];
  const float* bc  = (const float*)d_in[5];
  float* out = (float*)d_out;

  u16* T   = (u16*)d_ws;                        // [12800][2048] bf16
  u16* V   = T   + (size_t)MROWS * CDIM;        // [12800][2048] bf16
  u16* WvB = V   + (size_t)MROWS * CDIM;        // [2048][2048]  bf16
  u16* WcB = WvB + (size_t)CDIM * CDIM;         // [1024][2048]  bf16

  {
    int n4 = CDIM * CDIM / 4;
    cvt_kernel<<<(n4 + 255) / 256, 256, 0, stream>>>(Wv, WvB, n4);
  }
  {
    int n4 = ODIM * CDIM / 4;
    cvt_kernel<<<(n4 + 255) / 256, 256, 0, stream>>>(Wc, WcB, n4);
  }
  prep_kernel<<<BATCH * 32, 256, 0, stream>>>(x, pos, T);

  // GEMM1: [12800,2048]x[2048,2048]^T -> V ; grid 50*8=400 (%8==0)
  gemm256<1><<<(MROWS / 256) * (CDIM / 256), 512, 0, stream>>>(
      T, WvB, bv, V, MROWS, CDIM, CDIM, CDIM / 256);

  attn0_kernel<<<dim3(BATCH, NHEADS), 64, 0, stream>>>(V);

  // GEMM2: [12800,2048]x[1024,2048]^T -> out ; grid 50*4=200 (%8==0)
  gemm256<0><<<(MROWS / 256) * (ODIM / 256), 512, 0, stream>>>(
      V, WcB, bc, out, MROWS, ODIM, CDIM, ODIM / 256);
}